// Round 3
// baseline (1565.680 us; speedup 1.0000x reference)
//
#include <hip/hip_runtime.h>
#include <hip/hip_bf16.h>

#define U_CNT 100000
#define I_CNT 50000
#define N_CNT 150000
#define NNZ_CNT 6000000

// ---------------------------------------------------------------------------
// CSR build: histogram -> scan -> scatter into interleaved (col, val) pairs
// ---------------------------------------------------------------------------

__global__ void hist_kernel(const int* __restrict__ row, int* __restrict__ cnt, int nnz) {
    int e = blockIdx.x * 256 + threadIdx.x;
    if (e < nnz) atomicAdd(&cnt[row[e]], 1);
}

// Exclusive scan within blocks of 1024; writes per-block exclusive values and block sums.
__global__ void scan_block_kernel(const int* __restrict__ in, int* __restrict__ out,
                                  int* __restrict__ bsum, int n) {
    __shared__ int sm[1024];
    int t = threadIdx.x;
    int i = blockIdx.x * 1024 + t;
    int v = (i < n) ? in[i] : 0;
    sm[t] = v;
    __syncthreads();
    for (int off = 1; off < 1024; off <<= 1) {
        int u = (t >= off) ? sm[t - off] : 0;
        __syncthreads();
        sm[t] += u;
        __syncthreads();
    }
    if (i < n) out[i] = sm[t] - v;  // exclusive within block
    if (t == 1023 && bsum) bsum[blockIdx.x] = sm[1023];
}

__global__ void scan_fix_kernel(int* __restrict__ rp, const int* __restrict__ boff,
                                int* __restrict__ nxt, int n, int nnz) {
    int i = blockIdx.x * 1024 + threadIdx.x;
    if (i < n) {
        int v = rp[i] + boff[blockIdx.x];
        rp[i] = v;
        nxt[i] = v;
    }
    if (i == 0) rp[n] = nnz;
}

__global__ void scatter_kernel(const int* __restrict__ row, const int* __restrict__ col,
                               const float* __restrict__ val, int* __restrict__ nxt,
                               int2* __restrict__ pairs, int nnz) {
    int e = blockIdx.x * 256 + threadIdx.x;
    if (e >= nnz) return;
    int r = row[e];
    int p = atomicAdd(&nxt[r], 1);
    pairs[p] = make_int2(col[e], __float_as_int(val[e]));
}

// ---------------------------------------------------------------------------
// SpMM: one wave per row, lane = feature dim. Coalesced 256B gather per edge.
// Also accumulates into acc (first layer initializes).
// ---------------------------------------------------------------------------

__global__ __launch_bounds__(256) void spmm_kernel(
    const int* __restrict__ rp, const int2* __restrict__ pairs,
    const float* __restrict__ x, float* __restrict__ y,
    float* __restrict__ acc, int first)
{
    int wave = threadIdx.x >> 6;
    int lane = threadIdx.x & 63;
    int row = blockIdx.x * 4 + wave;
    if (row >= N_CNT) return;
    int s = rp[row];
    int e = rp[row + 1];
    float sum = 0.f;
    int i = s;
    for (; i + 3 < e; i += 4) {
        int2 p0 = pairs[i];
        int2 p1 = pairs[i + 1];
        int2 p2 = pairs[i + 2];
        int2 p3 = pairs[i + 3];
        float a0 = x[(size_t)p0.x * 64 + lane];
        float a1 = x[(size_t)p1.x * 64 + lane];
        float a2 = x[(size_t)p2.x * 64 + lane];
        float a3 = x[(size_t)p3.x * 64 + lane];
        sum += __int_as_float(p0.y) * a0;
        sum += __int_as_float(p1.y) * a1;
        sum += __int_as_float(p2.y) * a2;
        sum += __int_as_float(p3.y) * a3;
    }
    for (; i < e; ++i) {
        int2 p = pairs[i];
        sum += __int_as_float(p.y) * x[(size_t)p.x * 64 + lane];
    }
    size_t o = (size_t)row * 64 + lane;
    y[o] = sum;
    if (first) acc[o] = sum;
    else       acc[o] += sum;
}

// ---------------------------------------------------------------------------
// Fused 2-layer MLP: y = relu(x*W1^T + b1)*W2^T + b2, wave per row.
// W1, W2 staged transposed in LDS (conflict-free lane-consecutive reads).
// ---------------------------------------------------------------------------

__global__ __launch_bounds__(256) void mlp2_kernel(
    const float* __restrict__ xin, int nrows, float scale,
    const float* __restrict__ W1, const float* __restrict__ b1,
    const float* __restrict__ W2, const float* __restrict__ b2,
    float* __restrict__ out)
{
    __shared__ float W1T[64 * 64];
    __shared__ float W2T[64 * 64];
    __shared__ float rowbuf[4][64];
    __shared__ float hbuf[4][64];

    int t = threadIdx.x;
    for (int idx = t; idx < 4096; idx += 256) {
        int k = idx >> 6;     // source col
        int d = idx & 63;     // source row
        W1T[idx] = W1[d * 64 + k];   // W1T[k][d] = W1[d][k]
        W2T[idx] = W2[d * 64 + k];
    }
    __syncthreads();

    int wave = t >> 6;
    int lane = t & 63;
    float bb1 = b1[lane];
    float bb2 = b2[lane];

    for (int r = blockIdx.x * 4 + wave; r < nrows; r += gridDim.x * 4) {
        float xv = xin[(size_t)r * 64 + lane] * scale;
        rowbuf[wave][lane] = xv;
        float h = bb1;
#pragma unroll
        for (int k = 0; k < 64; ++k)
            h += rowbuf[wave][k] * W1T[k * 64 + lane];
        h = fmaxf(h, 0.f);
        hbuf[wave][lane] = h;
        float y = bb2;
#pragma unroll
        for (int k = 0; k < 64; ++k)
            y += hbuf[wave][k] * W2T[k * 64 + lane];
        out[(size_t)r * 64 + lane] = y;
    }
}

// ---------------------------------------------------------------------------

static inline int imin(int a, int b) { return a < b ? a : b; }

extern "C" void kernel_launch(void* const* d_in, const int* in_sizes, int n_in,
                              void* d_out, int out_size, void* d_ws, size_t ws_size,
                              hipStream_t stream)
{
    (void)in_sizes; (void)n_in; (void)out_size; (void)ws_size;

    const float* user_emb = (const float*)d_in[0];
    const float* item_emb = (const float*)d_in[1];
    const int*   erow     = (const int*)d_in[2];
    const int*   ecol     = (const int*)d_in[3];
    const float* evalv    = (const float*)d_in[4];
    const float* Wsg1 = (const float*)d_in[5];
    const float* bsg1 = (const float*)d_in[6];
    const float* Wsg2 = (const float*)d_in[7];
    const float* bsg2 = (const float*)d_in[8];
    const float* Wuf1 = (const float*)d_in[9];
    const float* buf1 = (const float*)d_in[10];
    const float* Wuf2 = (const float*)d_in[11];
    const float* buf2 = (const float*)d_in[12];
    const float* Wif1 = (const float*)d_in[13];
    const float* bif1 = (const float*)d_in[14];
    const float* Wif2 = (const float*)d_in[15];
    const float* bif2 = (const float*)d_in[16];

    float* out = (float*)d_out;

    const size_t XB = (size_t)N_CNT * 64;  // floats per node-embedding buffer

    // Workspace layout (~88.3 MB):
    char* ws = (char*)d_ws;
    float* acc   = (float*)ws;                                   // XB floats
    int2*  pairs = (int2*)(ws + XB * 4);                         // NNZ int2
    int*   cnt   = (int*)(ws + XB * 4 + (size_t)NNZ_CNT * 8);    // N
    int*   rp    = cnt + N_CNT;                                  // N+1 (+pad)
    int*   nxt   = rp + N_CNT + 4;                               // N
    int*   bsum  = nxt + N_CNT;                                  // 1024
    int*   boff  = bsum + 1024;                                  // 1024

    // x ping-pong buffers live in d_out (fully overwritten by MLP epilogue).
    float* xA = out;
    float* xB = out + XB;

    // ---- CSR build ----
    hipMemsetAsync(cnt, 0, N_CNT * sizeof(int), stream);
    hist_kernel<<<(NNZ_CNT + 255) / 256, 256, 0, stream>>>(erow, cnt, NNZ_CNT);
    int nb = (N_CNT + 1023) / 1024;  // 147
    scan_block_kernel<<<nb, 1024, 0, stream>>>(cnt, rp, bsum, N_CNT);
    scan_block_kernel<<<1, 1024, 0, stream>>>(bsum, boff, nullptr, nb);
    scan_fix_kernel<<<nb, 1024, 0, stream>>>(rp, boff, nxt, N_CNT, NNZ_CNT);
    scatter_kernel<<<(NNZ_CNT + 255) / 256, 256, 0, stream>>>(erow, ecol, evalv, nxt, pairs, NNZ_CNT);

    // ---- x0 = concat(user_emb, item_emb) ----
    hipMemcpyAsync(xA, user_emb, (size_t)U_CNT * 64 * 4, hipMemcpyDeviceToDevice, stream);
    hipMemcpyAsync(xA + (size_t)U_CNT * 64, item_emb, (size_t)I_CNT * 64 * 4,
                   hipMemcpyDeviceToDevice, stream);

    // ---- 3 propagation layers, accumulate into acc ----
    int sg = N_CNT / 4;  // 37500 blocks, 4 rows (waves) per block
    spmm_kernel<<<sg, 256, 0, stream>>>(rp, pairs, xA, xB, acc, 1);
    spmm_kernel<<<sg, 256, 0, stream>>>(rp, pairs, xB, xA, acc, 0);
    spmm_kernel<<<sg, 256, 0, stream>>>(rp, pairs, xA, xB, acc, 0);

    // ---- MLP heads (read acc only; overwrite d_out with final results) ----
    const float sc = 1.0f / 3.0f;
    int gb;
    gb = imin(1024, (N_CNT + 3) / 4);
    mlp2_kernel<<<gb, 256, 0, stream>>>(acc, N_CNT, sc, Wsg1, bsg1, Wsg2, bsg2, out);
    gb = imin(1024, (U_CNT + 3) / 4);
    mlp2_kernel<<<gb, 256, 0, stream>>>(acc, U_CNT, sc, Wuf1, buf1, Wuf2, buf2, out + XB);
    gb = imin(1024, (I_CNT + 3) / 4);
    mlp2_kernel<<<gb, 256, 0, stream>>>(acc + (size_t)U_CNT * 64, I_CNT, sc,
                                        Wif1, bif1, Wif2, bif2, out + XB + (size_t)U_CNT * 64);
}

// Round 4
// 1220.262 us; speedup vs baseline: 1.2831x; 1.2831x over previous
//
#include <hip/hip_runtime.h>
#include <hip/hip_bf16.h>

#define U_CNT 100000
#define I_CNT 50000
#define N_CNT 150000
#define NNZ_CNT 6000000
#define NB 586            // ceil(150000/256) buckets of 256 rows
#define BIN_BLOCKS 733    // ceil(6M/8192)

// ---------------------------------------------------------------------------
// Stage A: bucket histogram (LDS-aggregated)
// ---------------------------------------------------------------------------
__global__ __launch_bounds__(1024) void bucket_hist_kernel(
    const int* __restrict__ erow, int* __restrict__ bcnt, int nnz)
{
    __shared__ int lcnt[NB];
    int t = threadIdx.x;
    for (int i = t; i < NB; i += 1024) lcnt[i] = 0;
    __syncthreads();
    int base = blockIdx.x * 8192;
#pragma unroll
    for (int k = 0; k < 8; ++k) {
        int e = base + k * 1024 + t;
        if (e < nnz) atomicAdd(&lcnt[erow[e] >> 8], 1);
    }
    __syncthreads();
    for (int i = t; i < NB; i += 1024)
        if (lcnt[i]) atomicAdd(&bcnt[i], lcnt[i]);
}

// Stage B: scan 586 bucket counts (single block)
__global__ __launch_bounds__(1024) void bucket_scan_kernel(
    const int* __restrict__ bcnt, int* __restrict__ bbase, int* __restrict__ bnext)
{
    __shared__ int sm[1024];
    int t = threadIdx.x;
    int v = (t < NB) ? bcnt[t] : 0;
    sm[t] = v;
    __syncthreads();
    for (int off = 1; off < 1024; off <<= 1) {
        int u = (t >= off) ? sm[t - off] : 0;
        __syncthreads();
        sm[t] += u;
        __syncthreads();
    }
    if (t < NB) { int ex = sm[t] - v; bbase[t] = ex; bnext[t] = ex; }
}

// ---------------------------------------------------------------------------
// Stage C: bin edges into bucket-grouped records (rrow/rcol/rval in d_out).
// Block-level bulk reservation -> ~14-contiguous-record fronts per bucket,
// dirty-line working set ~0.2 MB -> no HBM write amplification.
// ---------------------------------------------------------------------------
__global__ __launch_bounds__(1024) void bin_kernel(
    const int* __restrict__ erow, const int* __restrict__ ecol,
    const float* __restrict__ evalv, int* __restrict__ bnext,
    int* __restrict__ rrow, int* __restrict__ rcol, float* __restrict__ rval,
    int nnz)
{
    __shared__ int lcnt[NB];
    __shared__ int lbase[NB];
    int t = threadIdx.x;
    for (int i = t; i < NB; i += 1024) lcnt[i] = 0;
    __syncthreads();
    int base = blockIdx.x * 8192;
    int rows[8];
#pragma unroll
    for (int k = 0; k < 8; ++k) {
        int e = base + k * 1024 + t;
        rows[k] = (e < nnz) ? erow[e] : -1;
        if (rows[k] >= 0) atomicAdd(&lcnt[rows[k] >> 8], 1);
    }
    __syncthreads();
    for (int i = t; i < NB; i += 1024)
        lbase[i] = lcnt[i] ? atomicAdd(&bnext[i], lcnt[i]) : 0;
    __syncthreads();
    for (int i = t; i < NB; i += 1024) lcnt[i] = 0;
    __syncthreads();
#pragma unroll
    for (int k = 0; k < 8; ++k) {
        int e = base + k * 1024 + t;
        if (rows[k] >= 0) {
            int b = rows[k] >> 8;
            int pos = lbase[b] + atomicAdd(&lcnt[b], 1);
            rrow[pos] = rows[k];
            rcol[pos] = ecol[e];
            rval[pos] = evalv[e];
        }
    }
}

// Stage D: per-row counts from bucket-sorted records (LDS counters, no global atomics)
__global__ __launch_bounds__(1024) void row_hist_kernel(
    const int* __restrict__ rrow, const int* __restrict__ bbase,
    const int* __restrict__ bcnt, int* __restrict__ cnt)
{
    __shared__ int lcnt[256];
    int b = blockIdx.x;
    int t = threadIdx.x;
    if (t < 256) lcnt[t] = 0;
    __syncthreads();
    int s = bbase[b], n = bcnt[b];
    for (int i = t; i < n; i += 1024) atomicAdd(&lcnt[rrow[s + i] & 255], 1);
    __syncthreads();
    int rowbase = b << 8;
    if (t < 256 && rowbase + t < N_CNT) cnt[rowbase + t] = lcnt[t];
}

// Stage E: 2-level exclusive scan over row counts -> rp
__global__ void scan_block_kernel(const int* __restrict__ in, int* __restrict__ out,
                                  int* __restrict__ bsum, int n) {
    __shared__ int sm[1024];
    int t = threadIdx.x;
    int i = blockIdx.x * 1024 + t;
    int v = (i < n) ? in[i] : 0;
    sm[t] = v;
    __syncthreads();
    for (int off = 1; off < 1024; off <<= 1) {
        int u = (t >= off) ? sm[t - off] : 0;
        __syncthreads();
        sm[t] += u;
        __syncthreads();
    }
    if (i < n) out[i] = sm[t] - v;
    if (t == 1023 && bsum) bsum[blockIdx.x] = sm[1023];
}

__global__ void scan_fix_kernel(int* __restrict__ rp, const int* __restrict__ boff,
                                int n, int nnz) {
    int i = blockIdx.x * 1024 + threadIdx.x;
    if (i < n) rp[i] += boff[blockIdx.x];
    if (i == 0) rp[n] = nnz;
}

// ---------------------------------------------------------------------------
// Stage F: place records into CSR pairs. One bucket at a time per block;
// destination region ~82 KB/bucket, 256 concurrent blocks -> ~2.6 MB/XCD in L2.
// Position via LDS atomics only.
// ---------------------------------------------------------------------------
__global__ __launch_bounds__(1024) void place_kernel(
    const int* __restrict__ rrow, const int* __restrict__ rcol,
    const float* __restrict__ rval, const int* __restrict__ bbase,
    const int* __restrict__ bcnt, const int* __restrict__ rp,
    int2* __restrict__ pairs)
{
    __shared__ int cur[256];
    int t = threadIdx.x;
    for (int b = blockIdx.x; b < NB; b += gridDim.x) {
        int rowbase = b << 8;
        if (t < 256) cur[t] = (rowbase + t < N_CNT) ? rp[rowbase + t] : 0;
        __syncthreads();
        int s = bbase[b], n = bcnt[b];
        for (int i = t; i < n; i += 1024) {
            int r = rrow[s + i];
            int p = atomicAdd(&cur[r & 255], 1);
            pairs[p] = make_int2(rcol[s + i], __float_as_int(rval[s + i]));
        }
        __syncthreads();
    }
}

// ---------------------------------------------------------------------------
// SpMM: wave per row, lane = feature dim. mode: 0=first (y,acc=), 1=mid
// (y=, acc+=), 2=last (acc+= only; dead y write skipped).
// ---------------------------------------------------------------------------
__global__ __launch_bounds__(256) void spmm_kernel(
    const int* __restrict__ rp, const int2* __restrict__ pairs,
    const float* __restrict__ x, float* __restrict__ y,
    float* __restrict__ acc, int mode)
{
    int wave = threadIdx.x >> 6;
    int lane = threadIdx.x & 63;
    int row = blockIdx.x * 4 + wave;
    if (row >= N_CNT) return;
    int s = rp[row];
    int e = rp[row + 1];
    float sum = 0.f;
    int i = s;
    for (; i + 3 < e; i += 4) {
        int2 p0 = pairs[i];
        int2 p1 = pairs[i + 1];
        int2 p2 = pairs[i + 2];
        int2 p3 = pairs[i + 3];
        float a0 = x[(size_t)p0.x * 64 + lane];
        float a1 = x[(size_t)p1.x * 64 + lane];
        float a2 = x[(size_t)p2.x * 64 + lane];
        float a3 = x[(size_t)p3.x * 64 + lane];
        sum += __int_as_float(p0.y) * a0;
        sum += __int_as_float(p1.y) * a1;
        sum += __int_as_float(p2.y) * a2;
        sum += __int_as_float(p3.y) * a3;
    }
    for (; i < e; ++i) {
        int2 p = pairs[i];
        sum += __int_as_float(p.y) * x[(size_t)p.x * 64 + lane];
    }
    size_t o = (size_t)row * 64 + lane;
    if (mode == 0)      { y[o] = sum; acc[o] = sum; }
    else if (mode == 1) { y[o] = sum; acc[o] += sum; }
    else                {             acc[o] += sum; }
}

// ---------------------------------------------------------------------------
// Fused 2-layer MLP, wave per row; W1/W2 transposed in LDS.
// ---------------------------------------------------------------------------
__global__ __launch_bounds__(256) void mlp2_kernel(
    const float* __restrict__ xin, int nrows, float scale,
    const float* __restrict__ W1, const float* __restrict__ b1,
    const float* __restrict__ W2, const float* __restrict__ b2,
    float* __restrict__ out)
{
    __shared__ float W1T[64 * 64];
    __shared__ float W2T[64 * 64];
    __shared__ float rowbuf[4][64];
    __shared__ float hbuf[4][64];

    int t = threadIdx.x;
    for (int idx = t; idx < 4096; idx += 256) {
        int k = idx >> 6;
        int d = idx & 63;
        W1T[idx] = W1[d * 64 + k];
        W2T[idx] = W2[d * 64 + k];
    }
    __syncthreads();

    int wave = t >> 6;
    int lane = t & 63;
    float bb1 = b1[lane];
    float bb2 = b2[lane];

    for (int r = blockIdx.x * 4 + wave; r < nrows; r += gridDim.x * 4) {
        float xv = xin[(size_t)r * 64 + lane] * scale;
        rowbuf[wave][lane] = xv;
        float h = bb1;
#pragma unroll
        for (int k = 0; k < 64; ++k)
            h += rowbuf[wave][k] * W1T[k * 64 + lane];
        h = fmaxf(h, 0.f);
        hbuf[wave][lane] = h;
        float y = bb2;
#pragma unroll
        for (int k = 0; k < 64; ++k)
            y += hbuf[wave][k] * W2T[k * 64 + lane];
        out[(size_t)r * 64 + lane] = y;
    }
}

// ---------------------------------------------------------------------------

static inline int imin(int a, int b) { return a < b ? a : b; }

extern "C" void kernel_launch(void* const* d_in, const int* in_sizes, int n_in,
                              void* d_out, int out_size, void* d_ws, size_t ws_size,
                              hipStream_t stream)
{
    (void)in_sizes; (void)n_in; (void)out_size; (void)ws_size;

    const float* user_emb = (const float*)d_in[0];
    const float* item_emb = (const float*)d_in[1];
    const int*   erow     = (const int*)d_in[2];
    const int*   ecol     = (const int*)d_in[3];
    const float* evalv    = (const float*)d_in[4];
    const float* Wsg1 = (const float*)d_in[5];
    const float* bsg1 = (const float*)d_in[6];
    const float* Wsg2 = (const float*)d_in[7];
    const float* bsg2 = (const float*)d_in[8];
    const float* Wuf1 = (const float*)d_in[9];
    const float* buf1 = (const float*)d_in[10];
    const float* Wuf2 = (const float*)d_in[11];
    const float* buf2 = (const float*)d_in[12];
    const float* Wif1 = (const float*)d_in[13];
    const float* bif1 = (const float*)d_in[14];
    const float* Wif2 = (const float*)d_in[15];
    const float* bif2 = (const float*)d_in[16];

    float* out = (float*)d_out;
    const size_t XB = (size_t)N_CNT * 64;

    // Workspace layout (~87 MB):
    char* ws = (char*)d_ws;
    float* acc   = (float*)ws;                                   // XB floats
    int2*  pairs = (int2*)(ws + XB * 4);                         // NNZ int2
    int*   cnt   = (int*)(ws + XB * 4 + (size_t)NNZ_CNT * 8);    // N
    int*   rp    = cnt + N_CNT;                                  // N+1 (+pad)
    int*   bcnt  = rp + N_CNT + 4;                               // NB
    int*   bbase = bcnt + NB;                                    // NB
    int*   bnext = bbase + NB;                                   // NB
    int*   bsum  = bnext + NB;                                   // 1024
    int*   boff  = bsum + 1024;                                  // 1024

    // Bucket-grouped records live in d_out (dead until embedding copy):
    int*   rrow = (int*)out;                 // 6M ints
    int*   rcol = rrow + NNZ_CNT;            // 6M ints
    float* rval = (float*)(rcol + NNZ_CNT);  // 6M floats (72 MB total <= 76.8)

    float* xA = out;
    float* xB = out + XB;

    // ---- CSR build (bucketed, amplification-free) ----
    hipMemsetAsync(bcnt, 0, NB * sizeof(int), stream);
    bucket_hist_kernel<<<BIN_BLOCKS, 1024, 0, stream>>>(erow, bcnt, NNZ_CNT);
    bucket_scan_kernel<<<1, 1024, 0, stream>>>(bcnt, bbase, bnext);
    bin_kernel<<<BIN_BLOCKS, 1024, 0, stream>>>(erow, ecol, evalv, bnext,
                                                rrow, rcol, rval, NNZ_CNT);
    row_hist_kernel<<<NB, 1024, 0, stream>>>(rrow, bbase, bcnt, cnt);
    int nb = (N_CNT + 1023) / 1024;  // 147
    scan_block_kernel<<<nb, 1024, 0, stream>>>(cnt, rp, bsum, N_CNT);
    scan_block_kernel<<<1, 1024, 0, stream>>>(bsum, boff, nullptr, nb);
    scan_fix_kernel<<<nb, 1024, 0, stream>>>(rp, boff, N_CNT, NNZ_CNT);
    place_kernel<<<256, 1024, 0, stream>>>(rrow, rcol, rval, bbase, bcnt, rp, pairs);

    // ---- x0 = concat(user_emb, item_emb) (overwrites records; sequential) ----
    hipMemcpyAsync(xA, user_emb, (size_t)U_CNT * 64 * 4, hipMemcpyDeviceToDevice, stream);
    hipMemcpyAsync(xA + (size_t)U_CNT * 64, item_emb, (size_t)I_CNT * 64 * 4,
                   hipMemcpyDeviceToDevice, stream);

    // ---- 3 propagation layers, accumulate into acc ----
    int sg = N_CNT / 4;
    spmm_kernel<<<sg, 256, 0, stream>>>(rp, pairs, xA, xB, acc, 0);
    spmm_kernel<<<sg, 256, 0, stream>>>(rp, pairs, xB, xA, acc, 1);
    spmm_kernel<<<sg, 256, 0, stream>>>(rp, pairs, xA, xB, acc, 2);

    // ---- MLP heads ----
    const float sc = 1.0f / 3.0f;
    int gb;
    gb = imin(1024, (N_CNT + 3) / 4);
    mlp2_kernel<<<gb, 256, 0, stream>>>(acc, N_CNT, sc, Wsg1, bsg1, Wsg2, bsg2, out);
    gb = imin(1024, (U_CNT + 3) / 4);
    mlp2_kernel<<<gb, 256, 0, stream>>>(acc, U_CNT, sc, Wuf1, buf1, Wuf2, buf2, out + XB);
    gb = imin(1024, (I_CNT + 3) / 4);
    mlp2_kernel<<<gb, 256, 0, stream>>>(acc + (size_t)U_CNT * 64, I_CNT, sc,
                                        Wif1, bif1, Wif2, bif2, out + XB + (size_t)U_CNT * 64);
}